// Round 2
// baseline (470.903 us; speedup 1.0000x reference)
//
#include <hip/hip_runtime.h>

// DeepFM fused: B=16384, D=1024, L=4.
// One persistent kernel: 256 blocks x 512 threads (8 waves), each block owns a
// 64-row slice of the batch. h (64x1024 bf16) stays in LDS across all 5 GEMMs;
// weights stream from global (L2-resident, shared by all blocks). Each wave
// computes 64 rows x 128 cols per layer in 128 AGPRs (16x16x32 bf16 MFMA).

#define DDIM 1024
#define BROWS 16384
#define HSTR 1032   // padded LDS row stride in shorts (+16B: uniform bank granules)

typedef __attribute__((ext_vector_type(8))) short s8v;   // 8 bf16
typedef __attribute__((ext_vector_type(4))) float f4v;   // 4 fp32

__device__ __forceinline__ unsigned short f2bf(float f) {
    unsigned int u = __float_as_uint(f);
    u += 0x7fffu + ((u >> 16) & 1u);   // round-to-nearest-even
    return (unsigned short)(u >> 16);
}

// ---------------- convert fp32 -> bf16 (weights) -------------------------
__global__ __launch_bounds__(256) void cvt_kernel(
    const float* __restrict__ in, unsigned short* __restrict__ out, int n)
{
    const int i = (blockIdx.x * 256 + threadIdx.x) * 4;
    if (i < n) {
        const float4 v = *(const float4*)(in + i);
        ushort4 o;
        o.x = f2bf(v.x); o.y = f2bf(v.y); o.z = f2bf(v.z); o.w = f2bf(v.w);
        *(ushort4*)(out + i) = o;
    }
}

// ---------------- fused 5-layer chain ------------------------------------
__global__ __launch_bounds__(512, 2) void fused_kernel(
    const float* __restrict__ x,             // [16384][1024] fp32
    const unsigned short* __restrict__ Wb,   // [4][1024][1024] bf16 (row-major [n][k])
    const float* __restrict__ bs,            // [4][1024]
    const unsigned short* __restrict__ Wob,  // [1024][1024] bf16
    const float* __restrict__ bo,            // [1024]
    float* __restrict__ out)                 // [16384][1024] fp32
{
    __shared__ unsigned short h[64 * HSTR];  // 129 KB
    __shared__ float rs[64];

    const int t = threadIdx.x;
    const int lane = t & 63;
    const int wave = t >> 6;                 // 0..7
    const int rowBase = blockIdx.x * 64;

    // ---- init: x fp32 -> bf16 into h, plus fp32 rowsums ----
    {
        const int r = t >> 3;                // 0..63
        const int cseg = (t & 7) * 128;
        const float* xr = x + (size_t)(rowBase + r) * DDIM + cseg;
        float s = 0.f;
        for (int c = 0; c < 128; c += 4) {
            const float4 v = *(const float4*)(xr + c);
            s += v.x + v.y + v.z + v.w;
            ushort4 o;
            o.x = f2bf(v.x); o.y = f2bf(v.y); o.z = f2bf(v.z); o.w = f2bf(v.w);
            *(ushort4*)&h[r * HSTR + cseg + c] = o;
        }
        s += __shfl_down(s, 4);
        s += __shfl_down(s, 2);
        s += __shfl_down(s, 1);
        if ((t & 7) == 0) rs[r] = s;
    }
    __syncthreads();

    const int colW = wave * 128;             // this wave's output col base
    const int mrow = lane & 15;              // fragment row/col within 16-block
    const int kq   = lane >> 4;              // k-quad 0..3 (8 elems each)
    const int quad = lane >> 4;              // C-layout row quad

    #pragma unroll 1
    for (int layer = 0; layer < 5; ++layer) {
        const unsigned short* W = (layer == 4) ? Wob : Wb + (size_t)layer * DDIM * DDIM;
        const float* bias = (layer == 4) ? bo : bs + (size_t)layer * DDIM;

        f4v acc[4][8] = {};   // [mi][ni] -> 128 AGPRs

        // per-lane weight base for this wave's col slice
        const unsigned short* wbase = W + (size_t)(colW + mrow) * DDIM + kq * 8;

        for (int k0 = 0; k0 < DDIM; k0 += 32) {
            s8v bfr[8];
            #pragma unroll
            for (int ni = 0; ni < 8; ++ni)
                bfr[ni] = *(const s8v*)(wbase + (size_t)ni * 16 * DDIM + k0);
            s8v af[4];
            #pragma unroll
            for (int mi = 0; mi < 4; ++mi)
                af[mi] = *(const s8v*)&h[(mi * 16 + mrow) * HSTR + k0 + kq * 8];
            #pragma unroll
            for (int mi = 0; mi < 4; ++mi)
                #pragma unroll
                for (int ni = 0; ni < 8; ++ni)
                    acc[mi][ni] = __builtin_amdgcn_mfma_f32_16x16x32_bf16(
                        af[mi], bfr[ni], acc[mi][ni], 0, 0, 0);
        }

        __syncthreads();   // all waves done reading h for this layer

        // Epilogue. C/D layout: col = lane&15, row = quad*4 + reg (m89/m91).
        if (layer < 4) {
            #pragma unroll
            for (int ni = 0; ni < 8; ++ni) {
                const int n = colW + ni * 16 + mrow;
                const float bv = bias[n];
                #pragma unroll
                for (int mi = 0; mi < 4; ++mi) {
                    #pragma unroll
                    for (int r = 0; r < 4; ++r) {
                        const int row = mi * 16 + quad * 4 + r;
                        float v = acc[mi][ni][r] + bv;
                        v = v > 0.f ? v : 0.f;
                        if (layer == 3) {
                            float it = x[(size_t)(rowBase + row) * DDIM + n] * rs[row];
                            it = it > 0.f ? it : 0.f;
                            v = 0.5f * (v + it);
                        }
                        h[row * HSTR + n] = f2bf(v);
                    }
                }
            }
            __syncthreads();   // h_next fully written
        } else {
            #pragma unroll
            for (int ni = 0; ni < 8; ++ni) {
                const int n = colW + ni * 16 + mrow;
                const float bv = bias[n];
                #pragma unroll
                for (int mi = 0; mi < 4; ++mi) {
                    #pragma unroll
                    for (int r = 0; r < 4; ++r) {
                        const int row = mi * 16 + quad * 4 + r;
                        out[(size_t)(rowBase + row) * DDIM + n] = acc[mi][ni][r] + bv;
                    }
                }
            }
        }
    }
}

extern "C" void kernel_launch(void* const* d_in, const int* in_sizes, int n_in,
                              void* d_out, int out_size, void* d_ws, size_t ws_size,
                              hipStream_t stream) {
    const float* x  = (const float*)d_in[0];
    const float* Ws = (const float*)d_in[1];
    const float* bs = (const float*)d_in[2];
    const float* Wo = (const float*)d_in[3];
    const float* bo = (const float*)d_in[4];
    float* out = (float*)d_out;

    char* ws = (char*)d_ws;
    unsigned short* wb  = (unsigned short*)(ws);             // 8 MB  Ws bf16
    unsigned short* wob = (unsigned short*)(ws + 8388608);   // 2 MB  Wo bf16

    cvt_kernel<<<(4 * DDIM * DDIM) / 1024, 256, 0, stream>>>(Ws, wb, 4 * DDIM * DDIM);
    cvt_kernel<<<(DDIM * DDIM) / 1024, 256, 0, stream>>>(Wo, wob, DDIM * DDIM);

    fused_kernel<<<BROWS / 64, 512, 0, stream>>>(x, wb, bs, wob, bo, out);
}

// Round 3
// 373.399 us; speedup vs baseline: 1.2611x; 1.2611x over previous
//
#include <hip/hip_runtime.h>

// DeepFM: B=16384, D=1024, L=4. Split-GEMM chain (round-1 structure) with:
//  - BK=64 per barrier round as two BK=32 LDS buffers (16 rounds, not 32)
//  - bf16 C stored via LDS transpose -> full-line 16B/lane stores (no write-allocate)
//  - layer-4 interactions read bf16 xb (LLC-warm) instead of fp32 x

#define DDIM 1024
#define BROWS 16384

typedef __attribute__((ext_vector_type(8))) short s8v;   // 8 bf16
typedef __attribute__((ext_vector_type(4))) float f4v;   // 4 fp32

__device__ __forceinline__ unsigned short f2bf(float f) {
    unsigned int u = __float_as_uint(f);
    u += 0x7fffu + ((u >> 16) & 1u);   // round-to-nearest-even
    return (unsigned short)(u >> 16);
}
__device__ __forceinline__ float bf2f(unsigned short u) {
    return __uint_as_float(((unsigned int)u) << 16);
}
__device__ __forceinline__ void gld16(const void* g, void* l) {
    __builtin_amdgcn_global_load_lds(
        (const __attribute__((address_space(1))) unsigned int*)g,
        (__attribute__((address_space(3))) unsigned int*)l, 16, 0, 0);
}

// ---------------- prep: x fp32 -> bf16, rowsum(x) fp32 -------------------
__global__ __launch_bounds__(256) void prep_kernel(
    const float* __restrict__ x, unsigned short* __restrict__ xb,
    float* __restrict__ rowsum)
{
    const int row = blockIdx.x;
    const int t = threadIdx.x;
    const float4 v = *(const float4*)(x + (size_t)row * DDIM + t * 4);
    ushort4 o;
    o.x = f2bf(v.x); o.y = f2bf(v.y); o.z = f2bf(v.z); o.w = f2bf(v.w);
    *(ushort4*)(xb + (size_t)row * DDIM + t * 4) = o;
    float s = v.x + v.y + v.z + v.w;
    #pragma unroll
    for (int off = 32; off > 0; off >>= 1) s += __shfl_down(s, off, 64);
    __shared__ float red[4];
    const int wave = t >> 6, lane = t & 63;
    if (lane == 0) red[wave] = s;
    __syncthreads();
    if (t == 0) rowsum[row] = red[0] + red[1] + red[2] + red[3];
}

// ---------------- convert all weights fp32 -> bf16 -----------------------
// out layout: [5][1024][1024] bf16; layers 0..3 from Ws, layer 4 from Wo.
__global__ __launch_bounds__(256) void cvt_kernel(
    const float* __restrict__ Ws, const float* __restrict__ Wo,
    unsigned short* __restrict__ out)
{
    const int i = (blockIdx.x * 256 + threadIdx.x) * 4;
    const float* src = (i < 4 * DDIM * DDIM) ? (Ws + i) : (Wo + (i - 4 * DDIM * DDIM));
    const float4 v = *(const float4*)src;
    ushort4 o;
    o.x = f2bf(v.x); o.y = f2bf(v.y); o.z = f2bf(v.z); o.w = f2bf(v.w);
    *(ushort4*)(out + i) = o;
}

// ---------------- GEMM: C = A(MxK) @ Bw(NxK)^T + bias --------------------
// MODE 0: out bf16 = relu(z)
// MODE 1: out bf16 = 0.5*(relu(z) + relu(xb*rowsum))   (layer 4 fusion)
// MODE 2: out fp32 = z                                  (final layer)
template <int MODE>
__global__ __launch_bounds__(256, 2) void gemm_bt(
    const unsigned short* __restrict__ A,
    const unsigned short* __restrict__ Bw,
    const float* __restrict__ bias,
    void* __restrict__ out,
    const unsigned short* __restrict__ xb,
    const float* __restrict__ rowsum)
{
    constexpr int K = DDIM, N = DDIM;
    // 4 x 8KB buffers: [0]=A k-lo, [1]=A k-hi, [2]=B k-lo, [3]=B k-hi.
    // Reused as 32KB C tile (128x128 bf16) in the epilogue.
    __shared__ unsigned short smem[4][128 * 32];

    const int t = threadIdx.x;
    const int wave = t >> 6, lane = t & 63;
    const int wm = wave & 1, wn = wave >> 1;       // 2x2 wave grid of 64x64
    const int rowBase = blockIdx.x * 128;
    const int colBase = blockIdx.y * 128;

    f4v acc[4][4] = {};

    const int c0r = t >> 2, c0k = (t & 3) * 8;     // staging: row, k-chunk
    const int mrow = lane & 15;
    const int koff = (lane >> 4) * 8;

    for (int kt = 0; kt < K; kt += 64) {
        if (kt) __syncthreads();
        const unsigned short* a0 = A  + (size_t)(rowBase + c0r) * K + kt + c0k;
        const unsigned short* b0 = Bw + (size_t)(colBase + c0r) * K + kt + c0k;
        gld16(a0,               (char*)smem[0] + t * 16);
        gld16(a0 + 64 * K,      (char*)smem[0] + (t + 256) * 16);
        gld16(b0,               (char*)smem[2] + t * 16);
        gld16(b0 + 64 * K,      (char*)smem[2] + (t + 256) * 16);
        gld16(a0 + 32,          (char*)smem[1] + t * 16);
        gld16(a0 + 64 * K + 32, (char*)smem[1] + (t + 256) * 16);
        gld16(b0 + 32,          (char*)smem[3] + t * 16);
        gld16(b0 + 64 * K + 32, (char*)smem[3] + (t + 256) * 16);
        __syncthreads();

        #pragma unroll
        for (int s = 0; s < 2; ++s) {
            s8v af[4], bfr[4];
            #pragma unroll
            for (int mi = 0; mi < 4; ++mi)
                af[mi] = *(const s8v*)&smem[s][(wm * 64 + mi * 16 + mrow) * 32 + koff];
            #pragma unroll
            for (int ni = 0; ni < 4; ++ni)
                bfr[ni] = *(const s8v*)&smem[2 + s][(wn * 64 + ni * 16 + mrow) * 32 + koff];
            #pragma unroll
            for (int mi = 0; mi < 4; ++mi)
                #pragma unroll
                for (int ni = 0; ni < 4; ++ni)
                    acc[mi][ni] = __builtin_amdgcn_mfma_f32_16x16x32_bf16(
                        af[mi], bfr[ni], acc[mi][ni], 0, 0, 0);
        }
    }

    // Epilogue. C/D layout: col = lane&15, row = (lane>>4)*4 + reg  (m89/m91)
    const int quad = lane >> 4;
    if (MODE == 2) {
        float* o = (float*)out;
        #pragma unroll
        for (int ni = 0; ni < 4; ++ni) {
            const int n = colBase + wn * 64 + ni * 16 + mrow;
            const float bv = bias[n];
            #pragma unroll
            for (int mi = 0; mi < 4; ++mi)
                #pragma unroll
                for (int r = 0; r < 4; ++r) {
                    const int row = rowBase + wm * 64 + mi * 16 + quad * 4 + r;
                    o[(size_t)row * N + n] = acc[mi][ni][r] + bv;
                }
        }
    } else {
        __syncthreads();                       // staging buffers now reusable
        unsigned short* sC = (unsigned short*)smem;   // [128][128] bf16
        #pragma unroll
        for (int ni = 0; ni < 4; ++ni) {
            const int n = wn * 64 + ni * 16 + mrow;
            const float bv = bias[colBase + n];
            #pragma unroll
            for (int mi = 0; mi < 4; ++mi)
                #pragma unroll
                for (int r = 0; r < 4; ++r) {
                    const int row = wm * 64 + mi * 16 + quad * 4 + r;
                    float v = acc[mi][ni][r] + bv;
                    v = v > 0.f ? v : 0.f;
                    sC[row * 128 + n] = f2bf(v);
                }
        }
        __syncthreads();
        unsigned short* o16 = (unsigned short*)out;
        #pragma unroll
        for (int i = 0; i < 8; ++i) {
            const int idx = t + i * 256;       // 0..2047 chunk id
            const int row = idx >> 4, ch = idx & 15;
            s8v c = *(const s8v*)&sC[row * 128 + ch * 8];
            if (MODE == 1) {
                const float rsv = rowsum[rowBase + row];
                const s8v xv = *(const s8v*)&xb[(size_t)(rowBase + row) * DDIM + colBase + ch * 8];
                #pragma unroll
                for (int j = 0; j < 8; ++j) {
                    float it = bf2f((unsigned short)xv[j]) * rsv;
                    it = it > 0.f ? it : 0.f;
                    const float v = 0.5f * (bf2f((unsigned short)c[j]) + it);
                    c[j] = (short)f2bf(v);
                }
            }
            *(s8v*)&o16[(size_t)(rowBase + row) * DDIM + colBase + ch * 8] = c;
        }
    }
}

extern "C" void kernel_launch(void* const* d_in, const int* in_sizes, int n_in,
                              void* d_out, int out_size, void* d_ws, size_t ws_size,
                              hipStream_t stream) {
    const float* x  = (const float*)d_in[0];
    const float* Ws = (const float*)d_in[1];
    const float* bs = (const float*)d_in[2];
    const float* Wo = (const float*)d_in[3];
    const float* bo = (const float*)d_in[4];
    float* out = (float*)d_out;

    char* ws = (char*)d_ws;
    unsigned short* xb  = (unsigned short*)(ws);                 // 32 MB bf16 x
    unsigned short* h0  = (unsigned short*)(ws + 33554432);      // 32 MB
    unsigned short* h1  = (unsigned short*)(ws + 67108864);      // 32 MB
    unsigned short* wb  = (unsigned short*)(ws + 100663296);     // 10 MB  all weights bf16
    float*          rsm = (float*)(ws + 111149056);              // 64 KB rowsum

    prep_kernel<<<BROWS, 256, 0, stream>>>(x, xb, rsm);
    cvt_kernel<<<(5 * DDIM * DDIM) / 1024, 256, 0, stream>>>(Ws, Wo, wb);

    const size_t WSZ = (size_t)DDIM * DDIM;
    dim3 g(BROWS / 128, DDIM / 128);
    gemm_bt<0><<<g, 256, 0, stream>>>(xb, wb,           bs,            h0, nullptr, nullptr);
    gemm_bt<0><<<g, 256, 0, stream>>>(h0, wb + 1 * WSZ, bs + 1 * DDIM, h1, nullptr, nullptr);
    gemm_bt<0><<<g, 256, 0, stream>>>(h1, wb + 2 * WSZ, bs + 2 * DDIM, h0, nullptr, nullptr);
    gemm_bt<1><<<g, 256, 0, stream>>>(h0, wb + 3 * WSZ, bs + 3 * DDIM, h1, xb, rsm);
    gemm_bt<2><<<g, 256, 0, stream>>>(h1, wb + 4 * WSZ, bo,            out, nullptr, nullptr);
}